// Round 10
// baseline (329.235 us; speedup 1.0000x reference)
//
#include <hip/hip_runtime.h>
#include <hip/hip_bf16.h>
#include <hip/hip_fp16.h>

// ---------------- constants ----------------
#define N_NODES 50000
#define N_EDGES 600000
#define N_GRAPHS 64
#define PCHUNK 16
#define SCAN_T 1024
#define SCAN_C ((N_NODES + SCAN_T - 1) / SCAN_T)  // 49

typedef __attribute__((ext_vector_type(8))) short bf16x8;
typedef __attribute__((ext_vector_type(4))) float f32x4;

// ---------------- bf16 helpers (round-to-nearest-even) ----------------
__device__ __forceinline__ unsigned short f2bf(float f) {
    unsigned int u = __float_as_uint(f);
    unsigned int r = u + 0x7fffu + ((u >> 16) & 1u);
    return (unsigned short)(r >> 16);
}
__device__ __forceinline__ float bf_lo(unsigned int u) { return __uint_as_float(u << 16); }
__device__ __forceinline__ float bf_hi(unsigned int u) { return __uint_as_float(u & 0xffff0000u); }
__device__ __forceinline__ float bf1(unsigned short s) {
    return __uint_as_float((unsigned int)s << 16);
}
// packed csr entry: (src << 16) | f16(norm)
__device__ __forceinline__ float pnorm(unsigned int e) {
    return __half2float(__ushort_as_half((unsigned short)(e & 0xffffu)));
}

// ---------------- fused degree count + weight repack ----------------
__device__ __forceinline__ void wprep_one(const float* W, unsigned short* Wp, int F, int idx) {
    int i = idx & 7;
    int lane = (idx >> 3) & 63;
    int ks = (idx >> 9) & 3;
    int ct = idx >> 11;
    int k = ks * 32 + (lane >> 4) * 8 + i;
    int col = ct * 16 + (lane & 15);
    Wp[idx] = f2bf(W[(size_t)k * F + col]);
}

__global__ __launch_bounds__(256) void deg_wprep(const int* __restrict__ dst,
                                                 int* __restrict__ degi, int E,
                                                 const float* __restrict__ W1,
                                                 const float* __restrict__ W2,
                                                 const float* __restrict__ W3,
                                                 const float* __restrict__ W4,
                                                 unsigned short* __restrict__ Wp1,
                                                 unsigned short* __restrict__ Wp2,
                                                 unsigned short* __restrict__ Wp3,
                                                 unsigned short* __restrict__ Wp4) {
    const int DEGB = (N_EDGES + 255) / 256;  // 2344
    int bid = blockIdx.x;
    if (bid < DEGB) {
        int i = bid * 256 + threadIdx.x;
        if (i < E) atomicAdd(&degi[dst[i]], 1);
    } else {
        int wb = bid - DEGB;
        if (wb < 64) wprep_one(W1, Wp1, 128, wb * 256 + threadIdx.x);
        else if (wb < 128) wprep_one(W2, Wp2, 128, (wb - 64) * 256 + threadIdx.x);
        else if (wb < 192) wprep_one(W3, Wp3, 128, (wb - 128) * 256 + threadIdx.x);
        else wprep_one(W4, Wp4, 64, (wb - 192) * 256 + threadIdx.x);
    }
}

// ---------------- single-block scan: rowptr/cursor + dis + gstart ----------------
__global__ __launch_bounds__(SCAN_T) void scan_all(const int* __restrict__ degi,
                                                   int* __restrict__ rowptr,
                                                   int* __restrict__ cursor,
                                                   float* __restrict__ dis,
                                                   const int* __restrict__ batch,
                                                   int* __restrict__ gstart) {
    __shared__ int s[SCAN_T];
    const int t = threadIdx.x;
    const int c0 = t * SCAN_C;

    int sum = 0;
#pragma unroll 1
    for (int j = 0; j < SCAN_C; ++j) {
        int i = c0 + j;
        if (i < N_NODES) sum += degi[i];
    }
    s[t] = sum;
    __syncthreads();
#pragma unroll
    for (int off = 1; off < SCAN_T; off <<= 1) {
        int v = (t >= off) ? s[t - off] : 0;
        __syncthreads();
        s[t] += v;
        __syncthreads();
    }
    int base = s[t] - sum;  // exclusive prefix of this chunk

#pragma unroll 1
    for (int j = 0; j < SCAN_C; ++j) {
        int i = c0 + j;
        if (i < N_NODES) {
            int d = degi[i];
            rowptr[i] = base;
            cursor[i] = base;
            dis[i] = rsqrtf((float)d + 1.0f);
            base += d;
        }
    }
    if (t == 0) rowptr[N_NODES] = N_EDGES;

    if (t <= N_GRAPHS) {
        int lo = 0, hi = N_NODES;
        while (lo < hi) {
            int mid = (lo + hi) >> 1;
            if (batch[mid] < t) lo = mid + 1; else hi = mid;
        }
        gstart[t] = lo;
    }
}

// ---------------- FUSED: mm1 (x @ W1 -> Ta) + CSR fill (packed 4B entries) ----------------
// blocks [0, MM1B): layer-1 MFMA matmul; blocks [MM1B, MM1B+CSRB): csr scatter.
// Both depend only on {Wp1} / {cursor, dis} which are ready after scan_all.
#define MM1B ((N_NODES + 63) / 64)        // 782
#define CSRB ((N_EDGES + 255) / 256)      // 2344

__global__ __launch_bounds__(256) void csrfill_mm1(const int* __restrict__ src,
                                                   const int* __restrict__ dst,
                                                   const float* __restrict__ dis,
                                                   int* __restrict__ cursor,
                                                   unsigned int* __restrict__ csr, int E,
                                                   const float* __restrict__ Xf,
                                                   const unsigned short* __restrict__ Wp,
                                                   unsigned short* __restrict__ T, int N) {
    if (blockIdx.x >= MM1B) {
        // ---- CSR fill ----
        int e = (blockIdx.x - MM1B) * 256 + threadIdx.x;
        if (e >= E) return;
        int s = src[e];
        int d = dst[e];
        float nrm = dis[s] * dis[d];
        unsigned short hb = __half_as_ushort(__float2half(nrm));
        int pos = atomicAdd(&cursor[d], 1);
        csr[pos] = ((unsigned int)s << 16) | (unsigned int)hb;
        return;
    }
    // ---- mm1 ----
    const int lane = threadIdx.x & 63;
    const int wave = threadIdx.x >> 6;
    const int r0 = blockIdx.x * 64 + wave * 16;
    const int kg = lane >> 4;
    const int rdrow = min(r0 + (lane & 15), N - 1);
    const float* xr = Xf + (size_t)rdrow * 128;

    bf16x8 a[4];
#pragma unroll
    for (int ks = 0; ks < 4; ++ks) {
        const int kb = ks * 32 + kg * 8;
        float4 x0 = *reinterpret_cast<const float4*>(xr + kb);
        float4 x1 = *reinterpret_cast<const float4*>(xr + kb + 4);
        float v[8] = {x0.x, x0.y, x0.z, x0.w, x1.x, x1.y, x1.z, x1.w};
#pragma unroll
        for (int i = 0; i < 8; ++i) a[ks][i] = (short)f2bf(v[i]);
    }

#pragma unroll
    for (int ct = 0; ct < 8; ++ct) {
        f32x4 acc = {0.f, 0.f, 0.f, 0.f};
#pragma unroll
        for (int ks = 0; ks < 4; ++ks) {
            bf16x8 b = *reinterpret_cast<const bf16x8*>(Wp + ((size_t)(ct * 4 + ks) * 64 + lane) * 8);
            acc = __builtin_amdgcn_mfma_f32_16x16x32_bf16(a[ks], b, acc, 0, 0, 0);
        }
        const int col = ct * 16 + (lane & 15);
#pragma unroll
        for (int r = 0; r < 4; ++r) {
            const int rowm = r0 + kg * 4 + r;
            if (rowm < N) T[(size_t)rowm * 128 + col] = f2bf(acc[r]);
        }
    }
}

// ---------------- edge-gather core for 128-feat bf16 rows (packed csr) ----------------
__device__ __forceinline__ void gather128(int beg, int end, const unsigned int* __restrict__ csr,
                                          const unsigned short* __restrict__ T, int lane,
                                          float& ax, float& ay) {
    int p = beg;
    for (; p + 8 <= end; p += 8) {
        unsigned int e0 = csr[p], e1 = csr[p + 1], e2 = csr[p + 2], e3 = csr[p + 3];
        unsigned int e4 = csr[p + 4], e5 = csr[p + 5], e6 = csr[p + 6], e7 = csr[p + 7];
        unsigned int r0 = *reinterpret_cast<const unsigned int*>(T + (size_t)(e0 >> 16) * 128 + lane * 2);
        unsigned int r1 = *reinterpret_cast<const unsigned int*>(T + (size_t)(e1 >> 16) * 128 + lane * 2);
        unsigned int r2 = *reinterpret_cast<const unsigned int*>(T + (size_t)(e2 >> 16) * 128 + lane * 2);
        unsigned int r3 = *reinterpret_cast<const unsigned int*>(T + (size_t)(e3 >> 16) * 128 + lane * 2);
        unsigned int r4 = *reinterpret_cast<const unsigned int*>(T + (size_t)(e4 >> 16) * 128 + lane * 2);
        unsigned int r5 = *reinterpret_cast<const unsigned int*>(T + (size_t)(e5 >> 16) * 128 + lane * 2);
        unsigned int r6 = *reinterpret_cast<const unsigned int*>(T + (size_t)(e6 >> 16) * 128 + lane * 2);
        unsigned int r7 = *reinterpret_cast<const unsigned int*>(T + (size_t)(e7 >> 16) * 128 + lane * 2);
        float n0 = pnorm(e0), n1 = pnorm(e1), n2 = pnorm(e2), n3 = pnorm(e3);
        float n4 = pnorm(e4), n5 = pnorm(e5), n6 = pnorm(e6), n7 = pnorm(e7);
        ax = fmaf(n0, bf_lo(r0), ax); ay = fmaf(n0, bf_hi(r0), ay);
        ax = fmaf(n1, bf_lo(r1), ax); ay = fmaf(n1, bf_hi(r1), ay);
        ax = fmaf(n2, bf_lo(r2), ax); ay = fmaf(n2, bf_hi(r2), ay);
        ax = fmaf(n3, bf_lo(r3), ax); ay = fmaf(n3, bf_hi(r3), ay);
        ax = fmaf(n4, bf_lo(r4), ax); ay = fmaf(n4, bf_hi(r4), ay);
        ax = fmaf(n5, bf_lo(r5), ax); ay = fmaf(n5, bf_hi(r5), ay);
        ax = fmaf(n6, bf_lo(r6), ax); ay = fmaf(n6, bf_hi(r6), ay);
        ax = fmaf(n7, bf_lo(r7), ax); ay = fmaf(n7, bf_hi(r7), ay);
    }
    for (; p + 4 <= end; p += 4) {
        unsigned int e0 = csr[p], e1 = csr[p + 1], e2 = csr[p + 2], e3 = csr[p + 3];
        unsigned int r0 = *reinterpret_cast<const unsigned int*>(T + (size_t)(e0 >> 16) * 128 + lane * 2);
        unsigned int r1 = *reinterpret_cast<const unsigned int*>(T + (size_t)(e1 >> 16) * 128 + lane * 2);
        unsigned int r2 = *reinterpret_cast<const unsigned int*>(T + (size_t)(e2 >> 16) * 128 + lane * 2);
        unsigned int r3 = *reinterpret_cast<const unsigned int*>(T + (size_t)(e3 >> 16) * 128 + lane * 2);
        float n0 = pnorm(e0), n1 = pnorm(e1), n2 = pnorm(e2), n3 = pnorm(e3);
        ax = fmaf(n0, bf_lo(r0), ax); ay = fmaf(n0, bf_hi(r0), ay);
        ax = fmaf(n1, bf_lo(r1), ax); ay = fmaf(n1, bf_hi(r1), ay);
        ax = fmaf(n2, bf_lo(r2), ax); ay = fmaf(n2, bf_hi(r2), ay);
        ax = fmaf(n3, bf_lo(r3), ax); ay = fmaf(n3, bf_hi(r3), ay);
    }
    for (; p < end; ++p) {
        unsigned int e = csr[p];
        float nrm = pnorm(e);
        unsigned int r = *reinterpret_cast<const unsigned int*>(T + (size_t)(e >> 16) * 128 + lane * 2);
        ax = fmaf(nrm, bf_lo(r), ax);
        ay = fmaf(nrm, bf_hi(r), ay);
    }
}

// ---------------- FUSED: agg(layer i) + relu + mm(layer i+1) ----------------
// block = 16 nodes (ONE MFMA tile), 8 waves (512 thr); wave w gathers nodes
// [r0 + w*2, +2) into LDS; all waves then MFMA, one ct per wave.
template <int FOUT>
__global__ __launch_bounds__(512) void aggmm(const int* __restrict__ rowptr,
                                             const unsigned int* __restrict__ csr,
                                             const float* __restrict__ dis,
                                             const float* __restrict__ b,
                                             const unsigned short* __restrict__ T,
                                             const unsigned short* __restrict__ Wp,
                                             unsigned short* __restrict__ Tout, int N) {
    __shared__ unsigned short hl[16][136];
    const int lane = threadIdx.x & 63;
    const int wave = threadIdx.x >> 6;
    const int r0 = blockIdx.x * 16;
    const float2 bb = *reinterpret_cast<const float2*>(b + lane * 2);

#pragma unroll 1
    for (int i = 0; i < 2; ++i) {
        const int row = wave * 2 + i;
        const int node = __builtin_amdgcn_readfirstlane(r0 + row);
        if (node >= N) {
            *reinterpret_cast<unsigned int*>(&hl[row][lane * 2]) = 0u;
            continue;
        }
        const int beg = rowptr[node];
        const int end = rowptr[node + 1];
        const float d = dis[node];
        const float d2 = d * d;
        unsigned int selfv =
            *reinterpret_cast<const unsigned int*>(T + (size_t)node * 128 + lane * 2);
        float ax = fmaf(bf_lo(selfv), d2, bb.x);
        float ay = fmaf(bf_hi(selfv), d2, bb.y);
        gather128(beg, end, csr, T, lane, ax, ay);
        unsigned int packed = ((unsigned int)f2bf(ay) << 16) | (unsigned int)f2bf(ax);
        *reinterpret_cast<unsigned int*>(&hl[row][lane * 2]) = packed;
    }
    __syncthreads();

    constexpr int NCT = FOUT / 16;  // 8 (F=128) or 4 (F=64)
    if (wave < NCT) {
        const int kg = lane >> 4;
        bf16x8 a[4];
#pragma unroll
        for (int ks = 0; ks < 4; ++ks) {
            bf16x8 av = *reinterpret_cast<const bf16x8*>(&hl[lane & 15][ks * 32 + kg * 8]);
#pragma unroll
            for (int i = 0; i < 8; ++i) av[i] = (av[i] < 0) ? (short)0 : av[i];
            a[ks] = av;
        }

        const int ct = wave;
        f32x4 acc = {0.f, 0.f, 0.f, 0.f};
#pragma unroll
        for (int ks = 0; ks < 4; ++ks) {
            bf16x8 bfr = *reinterpret_cast<const bf16x8*>(Wp + ((size_t)(ct * 4 + ks) * 64 + lane) * 8);
            acc = __builtin_amdgcn_mfma_f32_16x16x32_bf16(a[ks], bfr, acc, 0, 0, 0);
        }
        const int col = ct * 16 + (lane & 15);
#pragma unroll
        for (int r = 0; r < 4; ++r) {
            const int rowm = r0 + kg * 4 + r;
            if (rowm < N) Tout[(size_t)rowm * FOUT + col] = f2bf(acc[r]);
        }
    }
}

// ---------------- final aggregation (layer 4, F=64): T -> H bf16 ----------------
__global__ __launch_bounds__(256) void agg64(const int* __restrict__ rowptr,
                                             const unsigned int* __restrict__ csr,
                                             const float* __restrict__ dis,
                                             const float* __restrict__ b,
                                             const unsigned short* __restrict__ T,
                                             unsigned short* __restrict__ H, int N) {
    const int lane = threadIdx.x & 63;
    const int node = __builtin_amdgcn_readfirstlane((blockIdx.x * 256 + threadIdx.x) >> 6);
    if (node >= N) return;

    const int beg = rowptr[node];
    const int end = rowptr[node + 1];
    const float d = dis[node];
    const float d2 = d * d;
    float a = fmaf(bf1(T[(size_t)node * 64 + lane]), d2, b[lane]);

    int p = beg;
    for (; p + 8 <= end; p += 8) {
        unsigned int e0 = csr[p], e1 = csr[p + 1], e2 = csr[p + 2], e3 = csr[p + 3];
        unsigned int e4 = csr[p + 4], e5 = csr[p + 5], e6 = csr[p + 6], e7 = csr[p + 7];
        unsigned short v0 = T[(size_t)(e0 >> 16) * 64 + lane];
        unsigned short v1 = T[(size_t)(e1 >> 16) * 64 + lane];
        unsigned short v2 = T[(size_t)(e2 >> 16) * 64 + lane];
        unsigned short v3 = T[(size_t)(e3 >> 16) * 64 + lane];
        unsigned short v4 = T[(size_t)(e4 >> 16) * 64 + lane];
        unsigned short v5 = T[(size_t)(e5 >> 16) * 64 + lane];
        unsigned short v6 = T[(size_t)(e6 >> 16) * 64 + lane];
        unsigned short v7 = T[(size_t)(e7 >> 16) * 64 + lane];
        a = fmaf(pnorm(e0), bf1(v0), a);
        a = fmaf(pnorm(e1), bf1(v1), a);
        a = fmaf(pnorm(e2), bf1(v2), a);
        a = fmaf(pnorm(e3), bf1(v3), a);
        a = fmaf(pnorm(e4), bf1(v4), a);
        a = fmaf(pnorm(e5), bf1(v5), a);
        a = fmaf(pnorm(e6), bf1(v6), a);
        a = fmaf(pnorm(e7), bf1(v7), a);
    }
    for (; p + 4 <= end; p += 4) {
        unsigned int e0 = csr[p], e1 = csr[p + 1], e2 = csr[p + 2], e3 = csr[p + 3];
        unsigned short v0 = T[(size_t)(e0 >> 16) * 64 + lane];
        unsigned short v1 = T[(size_t)(e1 >> 16) * 64 + lane];
        unsigned short v2 = T[(size_t)(e2 >> 16) * 64 + lane];
        unsigned short v3 = T[(size_t)(e3 >> 16) * 64 + lane];
        a = fmaf(pnorm(e0), bf1(v0), a);
        a = fmaf(pnorm(e1), bf1(v1), a);
        a = fmaf(pnorm(e2), bf1(v2), a);
        a = fmaf(pnorm(e3), bf1(v3), a);
    }
    for (; p < end; ++p) {
        unsigned int e = csr[p];
        a = fmaf(pnorm(e), bf1(T[(size_t)(e >> 16) * 64 + lane]), a);
    }
    H[(size_t)node * 64 + lane] = f2bf(a);
}

// ---------------- pooling (two-stage deterministic; H is bf16) ----------------
__global__ __launch_bounds__(256) void pool_partial(const unsigned short* __restrict__ H,
                                                    const int* __restrict__ gstart,
                                                    float* __restrict__ partial) {
    const int g = blockIdx.x >> 4;
    const int c = blockIdx.x & (PCHUNK - 1);
    const int beg = gstart[g], end = gstart[g + 1];
    const int len = end - beg;
    const int csz = (len + PCHUNK - 1) / PCHUNK;
    const int cb = beg + c * csz;
    const int ce = min(cb + csz, end);
    const int lane = threadIdx.x & 63;
    const int wave = threadIdx.x >> 6;

    float acc = 0.0f;
    for (int n = cb + wave; n < ce; n += 4)
        acc += bf1(H[(size_t)n * 64 + lane]);

    __shared__ float s[4][64];
    s[wave][lane] = acc;
    __syncthreads();
    if (wave == 0)
        partial[(size_t)(g * PCHUNK + c) * 64 + lane] =
            s[0][lane] + s[1][lane] + s[2][lane] + s[3][lane];
}

__global__ __launch_bounds__(64) void pool_fin(const float* __restrict__ partial,
                                               const int* __restrict__ gstart,
                                               float* __restrict__ out) {
    const int g = blockIdx.x;
    const int lane = threadIdx.x;
    float v = 0.0f;
#pragma unroll
    for (int c = 0; c < PCHUNK; ++c) v += partial[(size_t)(g * PCHUNK + c) * 64 + lane];
    float cnt = (float)(gstart[g + 1] - gstart[g]);
    out[g * 64 + lane] = v / fmaxf(cnt, 1.0f);
}

// ---------------- launch ----------------
extern "C" void kernel_launch(void* const* d_in, const int* in_sizes, int n_in,
                              void* d_out, int out_size, void* d_ws, size_t ws_size,
                              hipStream_t stream) {
    const float* x = (const float*)d_in[0];
    const int* ei = (const int*)d_in[1];
    const int* batch = (const int*)d_in[2];
    const float* W1 = (const float*)d_in[3];
    const float* b1 = (const float*)d_in[4];
    const float* W2 = (const float*)d_in[5];
    const float* b2 = (const float*)d_in[6];
    const float* W3 = (const float*)d_in[7];
    const float* b3 = (const float*)d_in[8];
    const float* W4 = (const float*)d_in[9];
    const float* b4 = (const float*)d_in[10];

    const int N = N_NODES, E = N_EDGES;
    const int* src = ei;
    const int* dst = ei + E;

    // workspace layout (64B-aligned carve-outs)
    char* base = (char*)d_ws;
    size_t off = 0;
    auto carve = [&](size_t bytes) -> void* {
        off = (off + 63) & ~(size_t)63;
        void* p = base + off;
        off += bytes;
        return p;
    };
    unsigned short* Ta = (unsigned short*)carve((size_t)N * 128 * 2);  // bf16 ping
    unsigned short* Tb = (unsigned short*)carve((size_t)N * 128 * 2);  // bf16 pong
    unsigned short* H = (unsigned short*)carve((size_t)N * 64 * 2);   // bf16 (layer-4 out)
    int* degi = (int*)carve((size_t)N * 4);
    float* dis = (float*)carve((size_t)N * 4);
    int* rowptr = (int*)carve((size_t)(N + 1) * 4);
    int* cursor = (int*)carve((size_t)N * 4);
    unsigned int* csr = (unsigned int*)carve((size_t)E * 4);  // packed {src:16|f16 norm}
    int* gstart = (int*)carve(65 * 4);
    float* partial = (float*)carve((size_t)N_GRAPHS * PCHUNK * 64 * 4);
    unsigned short* Wp1 = (unsigned short*)carve(128 * 128 * 2);
    unsigned short* Wp2 = (unsigned short*)carve(128 * 128 * 2);
    unsigned short* Wp3 = (unsigned short*)carve(128 * 128 * 2);
    unsigned short* Wp4 = (unsigned short*)carve(128 * 64 * 2);

    hipMemsetAsync(degi, 0, N * sizeof(int), stream);

    // ---- prep: degree+wprep -> single-block scan -> fused csr_fill + mm1 ----
    const int DEGB = (E + 255) / 256;  // 2344
    deg_wprep<<<DEGB + 224, 256, 0, stream>>>(dst, degi, E, W1, W2, W3, W4,
                                              Wp1, Wp2, Wp3, Wp4);
    scan_all<<<1, SCAN_T, 0, stream>>>(degi, rowptr, cursor, dis, batch, gstart);
    csrfill_mm1<<<MM1B + CSRB, 256, 0, stream>>>(src, dst, dis, cursor, csr, E,
                                                 x, Wp1, Ta, N);

    const int FUS = (N + 15) / 16;  // 3125 (exact)

    // fused agg1 + relu + mm2 -> Tb
    aggmm<128><<<FUS, 512, 0, stream>>>(rowptr, csr, dis, b1, Ta, Wp2, Tb, N);
    // fused agg2 + relu + mm3 -> Ta
    aggmm<128><<<FUS, 512, 0, stream>>>(rowptr, csr, dis, b2, Tb, Wp3, Ta, N);
    // fused agg3 + relu + mm4 -> Tb (F=64)
    aggmm<64><<<FUS, 512, 0, stream>>>(rowptr, csr, dis, b3, Ta, Wp4, Tb, N);
    // final agg (layer 4) -> H
    agg64<<<(N * 64 + 255) / 256, 256, 0, stream>>>(rowptr, csr, dis, b4, Tb, H, N);

    // global mean pool (two-stage, deterministic)
    pool_partial<<<N_GRAPHS * PCHUNK, 256, 0, stream>>>(H, gstart, partial);
    pool_fin<<<N_GRAPHS, 64, 0, stream>>>(partial, gstart, (float*)d_out);
}

// Round 11
// 193.249 us; speedup vs baseline: 1.7037x; 1.7037x over previous
//
#include <hip/hip_runtime.h>
#include <hip/hip_bf16.h>
#include <hip/hip_fp16.h>

// ---------------- constants ----------------
#define N_NODES 50000
#define N_EDGES 600000
#define N_GRAPHS 64
#define PCHUNK 16

typedef __attribute__((ext_vector_type(8))) short bf16x8;
typedef __attribute__((ext_vector_type(4))) float f32x4;

// ---------------- bf16 helpers (round-to-nearest-even) ----------------
__device__ __forceinline__ unsigned short f2bf(float f) {
    unsigned int u = __float_as_uint(f);
    unsigned int r = u + 0x7fffu + ((u >> 16) & 1u);
    return (unsigned short)(r >> 16);
}
__device__ __forceinline__ float bf_lo(unsigned int u) { return __uint_as_float(u << 16); }
__device__ __forceinline__ float bf_hi(unsigned int u) { return __uint_as_float(u & 0xffff0000u); }
__device__ __forceinline__ float bf1(unsigned short s) {
    return __uint_as_float((unsigned int)s << 16);
}
// packed csr entry: (src << 16) | f16(norm)
__device__ __forceinline__ float pnorm(unsigned int e) {
    return __half2float(__ushort_as_half((unsigned short)(e & 0xffffu)));
}

// ---------------- fused degree count + weight repack ----------------
__device__ __forceinline__ void wprep_one(const float* W, unsigned short* Wp, int F, int idx) {
    int i = idx & 7;
    int lane = (idx >> 3) & 63;
    int ks = (idx >> 9) & 3;
    int ct = idx >> 11;
    int k = ks * 32 + (lane >> 4) * 8 + i;
    int col = ct * 16 + (lane & 15);
    Wp[idx] = f2bf(W[(size_t)k * F + col]);
}

__global__ __launch_bounds__(256) void deg_wprep(const int* __restrict__ dst,
                                                 int* __restrict__ degi, int E,
                                                 const float* __restrict__ W1,
                                                 const float* __restrict__ W2,
                                                 const float* __restrict__ W3,
                                                 const float* __restrict__ W4,
                                                 unsigned short* __restrict__ Wp1,
                                                 unsigned short* __restrict__ Wp2,
                                                 unsigned short* __restrict__ Wp3,
                                                 unsigned short* __restrict__ Wp4) {
    const int DEGB = (N_EDGES + 255) / 256;  // 2344
    int bid = blockIdx.x;
    if (bid < DEGB) {
        int i = bid * 256 + threadIdx.x;
        if (i < E) atomicAdd(&degi[dst[i]], 1);
    } else {
        int wb = bid - DEGB;
        if (wb < 64) wprep_one(W1, Wp1, 128, wb * 256 + threadIdx.x);
        else if (wb < 128) wprep_one(W2, Wp2, 128, (wb - 64) * 256 + threadIdx.x);
        else if (wb < 192) wprep_one(W3, Wp3, 128, (wb - 128) * 256 + threadIdx.x);
        else wprep_one(W4, Wp4, 64, (wb - 192) * 256 + threadIdx.x);
    }
}

// ---------------- prefix scan (3-kernel hierarchical; proven ~8us) ----------------
// scan_block also computes dis = rsqrt(deg+1)
__global__ __launch_bounds__(256) void scan_block(const int* __restrict__ in,
                                                  int* __restrict__ excl,
                                                  int* __restrict__ bsum,
                                                  float* __restrict__ dis, int N) {
    __shared__ int s[256];
    int i = blockIdx.x * 256 + threadIdx.x;
    int v = (i < N) ? in[i] : 0;
    s[threadIdx.x] = v;
    __syncthreads();
#pragma unroll
    for (int off = 1; off < 256; off <<= 1) {
        int t = (threadIdx.x >= off) ? s[threadIdx.x - off] : 0;
        __syncthreads();
        s[threadIdx.x] += t;
        __syncthreads();
    }
    if (i < N) {
        excl[i] = s[threadIdx.x] - v;
        dis[i] = rsqrtf((float)v + 1.0f);
    }
    if (threadIdx.x == 255) bsum[blockIdx.x] = s[255];
}

// scan_top also does the graph_bounds binary searches (batch sorted)
__global__ __launch_bounds__(256) void scan_top(const int* __restrict__ bsum,
                                                int* __restrict__ boff, int NB,
                                                const int* __restrict__ batch,
                                                int* __restrict__ gstart, int N) {
    __shared__ int s[256];
    int v = (threadIdx.x < NB) ? bsum[threadIdx.x] : 0;
    s[threadIdx.x] = v;
    __syncthreads();
#pragma unroll
    for (int off = 1; off < 256; off <<= 1) {
        int t = (threadIdx.x >= off) ? s[threadIdx.x - off] : 0;
        __syncthreads();
        s[threadIdx.x] += t;
        __syncthreads();
    }
    if (threadIdx.x < NB) boff[threadIdx.x] = s[threadIdx.x] - v;

    int g = threadIdx.x;
    if (g <= N_GRAPHS) {
        int lo = 0, hi = N;
        while (lo < hi) {
            int mid = (lo + hi) >> 1;
            if (batch[mid] < g) lo = mid + 1; else hi = mid;
        }
        gstart[g] = lo;
    }
}

__global__ __launch_bounds__(256) void scan_fix(const int* __restrict__ excl,
                                                const int* __restrict__ boff,
                                                int* __restrict__ rowptr,
                                                int* __restrict__ cursor, int N, int E) {
    int i = blockIdx.x * 256 + threadIdx.x;
    if (i < N) {
        int r = excl[i] + boff[blockIdx.x];
        rowptr[i] = r;
        cursor[i] = r;
    }
    if (i == 0) rowptr[N] = E;
}

// ---------------- FUSED: mm1 (x @ W1 -> Ta) + CSR fill (packed 4B entries) ----------------
#define MM1B ((N_NODES + 63) / 64)        // 782
#define CSRB ((N_EDGES + 255) / 256)      // 2344

__global__ __launch_bounds__(256) void csrfill_mm1(const int* __restrict__ src,
                                                   const int* __restrict__ dst,
                                                   const float* __restrict__ dis,
                                                   int* __restrict__ cursor,
                                                   unsigned int* __restrict__ csr, int E,
                                                   const float* __restrict__ Xf,
                                                   const unsigned short* __restrict__ Wp,
                                                   unsigned short* __restrict__ T, int N) {
    if (blockIdx.x >= MM1B) {
        // ---- CSR fill ----
        int e = (blockIdx.x - MM1B) * 256 + threadIdx.x;
        if (e >= E) return;
        int s = src[e];
        int d = dst[e];
        float nrm = dis[s] * dis[d];
        unsigned short hb = __half_as_ushort(__float2half(nrm));
        int pos = atomicAdd(&cursor[d], 1);
        csr[pos] = ((unsigned int)s << 16) | (unsigned int)hb;
        return;
    }
    // ---- mm1 ----
    const int lane = threadIdx.x & 63;
    const int wave = threadIdx.x >> 6;
    const int r0 = blockIdx.x * 64 + wave * 16;
    const int kg = lane >> 4;
    const int rdrow = min(r0 + (lane & 15), N - 1);
    const float* xr = Xf + (size_t)rdrow * 128;

    bf16x8 a[4];
#pragma unroll
    for (int ks = 0; ks < 4; ++ks) {
        const int kb = ks * 32 + kg * 8;
        float4 x0 = *reinterpret_cast<const float4*>(xr + kb);
        float4 x1 = *reinterpret_cast<const float4*>(xr + kb + 4);
        float v[8] = {x0.x, x0.y, x0.z, x0.w, x1.x, x1.y, x1.z, x1.w};
#pragma unroll
        for (int i = 0; i < 8; ++i) a[ks][i] = (short)f2bf(v[i]);
    }

#pragma unroll
    for (int ct = 0; ct < 8; ++ct) {
        f32x4 acc = {0.f, 0.f, 0.f, 0.f};
#pragma unroll
        for (int ks = 0; ks < 4; ++ks) {
            bf16x8 b = *reinterpret_cast<const bf16x8*>(Wp + ((size_t)(ct * 4 + ks) * 64 + lane) * 8);
            acc = __builtin_amdgcn_mfma_f32_16x16x32_bf16(a[ks], b, acc, 0, 0, 0);
        }
        const int col = ct * 16 + (lane & 15);
#pragma unroll
        for (int r = 0; r < 4; ++r) {
            const int rowm = r0 + kg * 4 + r;
            if (rowm < N) T[(size_t)rowm * 128 + col] = f2bf(acc[r]);
        }
    }
}

// ---------------- edge-gather core for 128-feat bf16 rows (packed csr) ----------------
__device__ __forceinline__ void gather128(int beg, int end, const unsigned int* __restrict__ csr,
                                          const unsigned short* __restrict__ T, int lane,
                                          float& ax, float& ay) {
    int p = beg;
    for (; p + 8 <= end; p += 8) {
        unsigned int e0 = csr[p], e1 = csr[p + 1], e2 = csr[p + 2], e3 = csr[p + 3];
        unsigned int e4 = csr[p + 4], e5 = csr[p + 5], e6 = csr[p + 6], e7 = csr[p + 7];
        unsigned int r0 = *reinterpret_cast<const unsigned int*>(T + (size_t)(e0 >> 16) * 128 + lane * 2);
        unsigned int r1 = *reinterpret_cast<const unsigned int*>(T + (size_t)(e1 >> 16) * 128 + lane * 2);
        unsigned int r2 = *reinterpret_cast<const unsigned int*>(T + (size_t)(e2 >> 16) * 128 + lane * 2);
        unsigned int r3 = *reinterpret_cast<const unsigned int*>(T + (size_t)(e3 >> 16) * 128 + lane * 2);
        unsigned int r4 = *reinterpret_cast<const unsigned int*>(T + (size_t)(e4 >> 16) * 128 + lane * 2);
        unsigned int r5 = *reinterpret_cast<const unsigned int*>(T + (size_t)(e5 >> 16) * 128 + lane * 2);
        unsigned int r6 = *reinterpret_cast<const unsigned int*>(T + (size_t)(e6 >> 16) * 128 + lane * 2);
        unsigned int r7 = *reinterpret_cast<const unsigned int*>(T + (size_t)(e7 >> 16) * 128 + lane * 2);
        float n0 = pnorm(e0), n1 = pnorm(e1), n2 = pnorm(e2), n3 = pnorm(e3);
        float n4 = pnorm(e4), n5 = pnorm(e5), n6 = pnorm(e6), n7 = pnorm(e7);
        ax = fmaf(n0, bf_lo(r0), ax); ay = fmaf(n0, bf_hi(r0), ay);
        ax = fmaf(n1, bf_lo(r1), ax); ay = fmaf(n1, bf_hi(r1), ay);
        ax = fmaf(n2, bf_lo(r2), ax); ay = fmaf(n2, bf_hi(r2), ay);
        ax = fmaf(n3, bf_lo(r3), ax); ay = fmaf(n3, bf_hi(r3), ay);
        ax = fmaf(n4, bf_lo(r4), ax); ay = fmaf(n4, bf_hi(r4), ay);
        ax = fmaf(n5, bf_lo(r5), ax); ay = fmaf(n5, bf_hi(r5), ay);
        ax = fmaf(n6, bf_lo(r6), ax); ay = fmaf(n6, bf_hi(r6), ay);
        ax = fmaf(n7, bf_lo(r7), ax); ay = fmaf(n7, bf_hi(r7), ay);
    }
    for (; p + 4 <= end; p += 4) {
        unsigned int e0 = csr[p], e1 = csr[p + 1], e2 = csr[p + 2], e3 = csr[p + 3];
        unsigned int r0 = *reinterpret_cast<const unsigned int*>(T + (size_t)(e0 >> 16) * 128 + lane * 2);
        unsigned int r1 = *reinterpret_cast<const unsigned int*>(T + (size_t)(e1 >> 16) * 128 + lane * 2);
        unsigned int r2 = *reinterpret_cast<const unsigned int*>(T + (size_t)(e2 >> 16) * 128 + lane * 2);
        unsigned int r3 = *reinterpret_cast<const unsigned int*>(T + (size_t)(e3 >> 16) * 128 + lane * 2);
        float n0 = pnorm(e0), n1 = pnorm(e1), n2 = pnorm(e2), n3 = pnorm(e3);
        ax = fmaf(n0, bf_lo(r0), ax); ay = fmaf(n0, bf_hi(r0), ay);
        ax = fmaf(n1, bf_lo(r1), ax); ay = fmaf(n1, bf_hi(r1), ay);
        ax = fmaf(n2, bf_lo(r2), ax); ay = fmaf(n2, bf_hi(r2), ay);
        ax = fmaf(n3, bf_lo(r3), ax); ay = fmaf(n3, bf_hi(r3), ay);
    }
    for (; p < end; ++p) {
        unsigned int e = csr[p];
        float nrm = pnorm(e);
        unsigned int r = *reinterpret_cast<const unsigned int*>(T + (size_t)(e >> 16) * 128 + lane * 2);
        ax = fmaf(nrm, bf_lo(r), ax);
        ay = fmaf(nrm, bf_hi(r), ay);
    }
}

// ---------------- FUSED: agg(layer i) + relu + mm(layer i+1) ----------------
// block = 16 nodes (ONE MFMA tile), 8 waves (512 thr); wave w gathers nodes
// [r0 + w*2, +2) into LDS; all waves then MFMA, one ct per wave.
template <int FOUT>
__global__ __launch_bounds__(512) void aggmm(const int* __restrict__ rowptr,
                                             const unsigned int* __restrict__ csr,
                                             const float* __restrict__ dis,
                                             const float* __restrict__ b,
                                             const unsigned short* __restrict__ T,
                                             const unsigned short* __restrict__ Wp,
                                             unsigned short* __restrict__ Tout, int N) {
    __shared__ unsigned short hl[16][136];
    const int lane = threadIdx.x & 63;
    const int wave = threadIdx.x >> 6;
    const int r0 = blockIdx.x * 16;
    const float2 bb = *reinterpret_cast<const float2*>(b + lane * 2);

#pragma unroll 1
    for (int i = 0; i < 2; ++i) {
        const int row = wave * 2 + i;
        const int node = __builtin_amdgcn_readfirstlane(r0 + row);
        if (node >= N) {
            *reinterpret_cast<unsigned int*>(&hl[row][lane * 2]) = 0u;
            continue;
        }
        const int beg = rowptr[node];
        const int end = rowptr[node + 1];
        const float d = dis[node];
        const float d2 = d * d;
        unsigned int selfv =
            *reinterpret_cast<const unsigned int*>(T + (size_t)node * 128 + lane * 2);
        float ax = fmaf(bf_lo(selfv), d2, bb.x);
        float ay = fmaf(bf_hi(selfv), d2, bb.y);
        gather128(beg, end, csr, T, lane, ax, ay);
        unsigned int packed = ((unsigned int)f2bf(ay) << 16) | (unsigned int)f2bf(ax);
        *reinterpret_cast<unsigned int*>(&hl[row][lane * 2]) = packed;
    }
    __syncthreads();

    constexpr int NCT = FOUT / 16;  // 8 (F=128) or 4 (F=64)
    if (wave < NCT) {
        const int kg = lane >> 4;
        bf16x8 a[4];
#pragma unroll
        for (int ks = 0; ks < 4; ++ks) {
            bf16x8 av = *reinterpret_cast<const bf16x8*>(&hl[lane & 15][ks * 32 + kg * 8]);
#pragma unroll
            for (int i = 0; i < 8; ++i) av[i] = (av[i] < 0) ? (short)0 : av[i];
            a[ks] = av;
        }

        const int ct = wave;
        f32x4 acc = {0.f, 0.f, 0.f, 0.f};
#pragma unroll
        for (int ks = 0; ks < 4; ++ks) {
            bf16x8 bfr = *reinterpret_cast<const bf16x8*>(Wp + ((size_t)(ct * 4 + ks) * 64 + lane) * 8);
            acc = __builtin_amdgcn_mfma_f32_16x16x32_bf16(a[ks], bfr, acc, 0, 0, 0);
        }
        const int col = ct * 16 + (lane & 15);
#pragma unroll
        for (int r = 0; r < 4; ++r) {
            const int rowm = r0 + kg * 4 + r;
            if (rowm < N) Tout[(size_t)rowm * FOUT + col] = f2bf(acc[r]);
        }
    }
}

// ---------------- final aggregation (layer 4, F=64): T -> H bf16 ----------------
__global__ __launch_bounds__(256) void agg64(const int* __restrict__ rowptr,
                                             const unsigned int* __restrict__ csr,
                                             const float* __restrict__ dis,
                                             const float* __restrict__ b,
                                             const unsigned short* __restrict__ T,
                                             unsigned short* __restrict__ H, int N) {
    const int lane = threadIdx.x & 63;
    const int node = __builtin_amdgcn_readfirstlane((blockIdx.x * 256 + threadIdx.x) >> 6);
    if (node >= N) return;

    const int beg = rowptr[node];
    const int end = rowptr[node + 1];
    const float d = dis[node];
    const float d2 = d * d;
    float a = fmaf(bf1(T[(size_t)node * 64 + lane]), d2, b[lane]);

    int p = beg;
    for (; p + 8 <= end; p += 8) {
        unsigned int e0 = csr[p], e1 = csr[p + 1], e2 = csr[p + 2], e3 = csr[p + 3];
        unsigned int e4 = csr[p + 4], e5 = csr[p + 5], e6 = csr[p + 6], e7 = csr[p + 7];
        unsigned short v0 = T[(size_t)(e0 >> 16) * 64 + lane];
        unsigned short v1 = T[(size_t)(e1 >> 16) * 64 + lane];
        unsigned short v2 = T[(size_t)(e2 >> 16) * 64 + lane];
        unsigned short v3 = T[(size_t)(e3 >> 16) * 64 + lane];
        unsigned short v4 = T[(size_t)(e4 >> 16) * 64 + lane];
        unsigned short v5 = T[(size_t)(e5 >> 16) * 64 + lane];
        unsigned short v6 = T[(size_t)(e6 >> 16) * 64 + lane];
        unsigned short v7 = T[(size_t)(e7 >> 16) * 64 + lane];
        a = fmaf(pnorm(e0), bf1(v0), a);
        a = fmaf(pnorm(e1), bf1(v1), a);
        a = fmaf(pnorm(e2), bf1(v2), a);
        a = fmaf(pnorm(e3), bf1(v3), a);
        a = fmaf(pnorm(e4), bf1(v4), a);
        a = fmaf(pnorm(e5), bf1(v5), a);
        a = fmaf(pnorm(e6), bf1(v6), a);
        a = fmaf(pnorm(e7), bf1(v7), a);
    }
    for (; p + 4 <= end; p += 4) {
        unsigned int e0 = csr[p], e1 = csr[p + 1], e2 = csr[p + 2], e3 = csr[p + 3];
        unsigned short v0 = T[(size_t)(e0 >> 16) * 64 + lane];
        unsigned short v1 = T[(size_t)(e1 >> 16) * 64 + lane];
        unsigned short v2 = T[(size_t)(e2 >> 16) * 64 + lane];
        unsigned short v3 = T[(size_t)(e3 >> 16) * 64 + lane];
        a = fmaf(pnorm(e0), bf1(v0), a);
        a = fmaf(pnorm(e1), bf1(v1), a);
        a = fmaf(pnorm(e2), bf1(v2), a);
        a = fmaf(pnorm(e3), bf1(v3), a);
    }
    for (; p < end; ++p) {
        unsigned int e = csr[p];
        a = fmaf(pnorm(e), bf1(T[(size_t)(e >> 16) * 64 + lane]), a);
    }
    H[(size_t)node * 64 + lane] = f2bf(a);
}

// ---------------- pooling (two-stage deterministic; H is bf16) ----------------
__global__ __launch_bounds__(256) void pool_partial(const unsigned short* __restrict__ H,
                                                    const int* __restrict__ gstart,
                                                    float* __restrict__ partial) {
    const int g = blockIdx.x >> 4;
    const int c = blockIdx.x & (PCHUNK - 1);
    const int beg = gstart[g], end = gstart[g + 1];
    const int len = end - beg;
    const int csz = (len + PCHUNK - 1) / PCHUNK;
    const int cb = beg + c * csz;
    const int ce = min(cb + csz, end);
    const int lane = threadIdx.x & 63;
    const int wave = threadIdx.x >> 6;

    float acc = 0.0f;
    for (int n = cb + wave; n < ce; n += 4)
        acc += bf1(H[(size_t)n * 64 + lane]);

    __shared__ float s[4][64];
    s[wave][lane] = acc;
    __syncthreads();
    if (wave == 0)
        partial[(size_t)(g * PCHUNK + c) * 64 + lane] =
            s[0][lane] + s[1][lane] + s[2][lane] + s[3][lane];
}

__global__ __launch_bounds__(64) void pool_fin(const float* __restrict__ partial,
                                               const int* __restrict__ gstart,
                                               float* __restrict__ out) {
    const int g = blockIdx.x;
    const int lane = threadIdx.x;
    float v = 0.0f;
#pragma unroll
    for (int c = 0; c < PCHUNK; ++c) v += partial[(size_t)(g * PCHUNK + c) * 64 + lane];
    float cnt = (float)(gstart[g + 1] - gstart[g]);
    out[g * 64 + lane] = v / fmaxf(cnt, 1.0f);
}

// ---------------- launch ----------------
extern "C" void kernel_launch(void* const* d_in, const int* in_sizes, int n_in,
                              void* d_out, int out_size, void* d_ws, size_t ws_size,
                              hipStream_t stream) {
    const float* x = (const float*)d_in[0];
    const int* ei = (const int*)d_in[1];
    const int* batch = (const int*)d_in[2];
    const float* W1 = (const float*)d_in[3];
    const float* b1 = (const float*)d_in[4];
    const float* W2 = (const float*)d_in[5];
    const float* b2 = (const float*)d_in[6];
    const float* W3 = (const float*)d_in[7];
    const float* b3 = (const float*)d_in[8];
    const float* W4 = (const float*)d_in[9];
    const float* b4 = (const float*)d_in[10];

    const int N = N_NODES, E = N_EDGES;
    const int* src = ei;
    const int* dst = ei + E;

    // workspace layout (64B-aligned carve-outs)
    char* base = (char*)d_ws;
    size_t off = 0;
    auto carve = [&](size_t bytes) -> void* {
        off = (off + 63) & ~(size_t)63;
        void* p = base + off;
        off += bytes;
        return p;
    };
    unsigned short* Ta = (unsigned short*)carve((size_t)N * 128 * 2);  // bf16 ping
    unsigned short* Tb = (unsigned short*)carve((size_t)N * 128 * 2);  // bf16 pong
    unsigned short* H = (unsigned short*)carve((size_t)N * 64 * 2);   // bf16 (layer-4 out)
    int* degi = (int*)carve((size_t)N * 4);
    float* dis = (float*)carve((size_t)N * 4);
    int* rowptr = (int*)carve((size_t)(N + 1) * 4);
    int* cursor = (int*)carve((size_t)N * 4);
    int* excl = (int*)carve((size_t)N * 4);
    int* bsum = (int*)carve(256 * 4);
    int* boff = (int*)carve(256 * 4);
    unsigned int* csr = (unsigned int*)carve((size_t)E * 4);  // packed {src:16|f16 norm}
    int* gstart = (int*)carve(65 * 4);
    float* partial = (float*)carve((size_t)N_GRAPHS * PCHUNK * 64 * 4);
    unsigned short* Wp1 = (unsigned short*)carve(128 * 128 * 2);
    unsigned short* Wp2 = (unsigned short*)carve(128 * 128 * 2);
    unsigned short* Wp3 = (unsigned short*)carve(128 * 128 * 2);
    unsigned short* Wp4 = (unsigned short*)carve(128 * 64 * 2);

    hipMemsetAsync(degi, 0, N * sizeof(int), stream);

    // ---- prep: degree+wprep -> 3-kernel scan -> fused csr_fill + mm1 ----
    const int NB = (N + 255) / 256;    // 196
    const int DEGB = (E + 255) / 256;  // 2344
    deg_wprep<<<DEGB + 224, 256, 0, stream>>>(dst, degi, E, W1, W2, W3, W4,
                                              Wp1, Wp2, Wp3, Wp4);
    scan_block<<<NB, 256, 0, stream>>>(degi, excl, bsum, dis, N);
    scan_top<<<1, 256, 0, stream>>>(bsum, boff, NB, batch, gstart, N);
    scan_fix<<<NB, 256, 0, stream>>>(excl, boff, rowptr, cursor, N, E);
    csrfill_mm1<<<MM1B + CSRB, 256, 0, stream>>>(src, dst, dis, cursor, csr, E,
                                                 x, Wp1, Ta, N);

    const int FUS = (N + 15) / 16;  // 3125 (exact)

    // fused agg1 + relu + mm2 -> Tb
    aggmm<128><<<FUS, 512, 0, stream>>>(rowptr, csr, dis, b1, Ta, Wp2, Tb, N);
    // fused agg2 + relu + mm3 -> Ta
    aggmm<128><<<FUS, 512, 0, stream>>>(rowptr, csr, dis, b2, Tb, Wp3, Ta, N);
    // fused agg3 + relu + mm4 -> Tb (F=64)
    aggmm<64><<<FUS, 512, 0, stream>>>(rowptr, csr, dis, b3, Ta, Wp4, Tb, N);
    // final agg (layer 4) -> H
    agg64<<<(N * 64 + 255) / 256, 256, 0, stream>>>(rowptr, csr, dis, b4, Tb, H, N);

    // global mean pool (two-stage, deterministic)
    pool_partial<<<N_GRAPHS * PCHUNK, 256, 0, stream>>>(H, gstart, partial);
    pool_fin<<<N_GRAPHS, 64, 0, stream>>>(partial, gstart, (float*)d_out);
}

// Round 12
// 181.760 us; speedup vs baseline: 1.8114x; 1.0632x over previous
//
#include <hip/hip_runtime.h>
#include <hip/hip_bf16.h>
#include <hip/hip_fp16.h>

// ---------------- constants ----------------
#define N_NODES 50000
#define N_EDGES 600000
#define N_GRAPHS 64
#define PCHUNK 16

typedef __attribute__((ext_vector_type(8))) short bf16x8;
typedef __attribute__((ext_vector_type(4))) float f32x4;

// ---------------- bf16 helpers (round-to-nearest-even) ----------------
__device__ __forceinline__ unsigned short f2bf(float f) {
    unsigned int u = __float_as_uint(f);
    unsigned int r = u + 0x7fffu + ((u >> 16) & 1u);
    return (unsigned short)(r >> 16);
}
__device__ __forceinline__ float bf_lo(unsigned int u) { return __uint_as_float(u << 16); }
__device__ __forceinline__ float bf_hi(unsigned int u) { return __uint_as_float(u & 0xffff0000u); }
__device__ __forceinline__ float bf1(unsigned short s) {
    return __uint_as_float((unsigned int)s << 16);
}
// packed csr entry: (src << 16) | f16(norm)
__device__ __forceinline__ float pnorm(unsigned int e) {
    return __half2float(__ushort_as_half((unsigned short)(e & 0xffffu)));
}

// ---------------- fused degree count + weight repack ----------------
__device__ __forceinline__ void wprep_one(const float* W, unsigned short* Wp, int F, int idx) {
    int i = idx & 7;
    int lane = (idx >> 3) & 63;
    int ks = (idx >> 9) & 3;
    int ct = idx >> 11;
    int k = ks * 32 + (lane >> 4) * 8 + i;
    int col = ct * 16 + (lane & 15);
    Wp[idx] = f2bf(W[(size_t)k * F + col]);
}

__global__ __launch_bounds__(256) void deg_wprep(const int* __restrict__ dst,
                                                 int* __restrict__ degi, int E,
                                                 const float* __restrict__ W1,
                                                 const float* __restrict__ W2,
                                                 const float* __restrict__ W3,
                                                 const float* __restrict__ W4,
                                                 unsigned short* __restrict__ Wp1,
                                                 unsigned short* __restrict__ Wp2,
                                                 unsigned short* __restrict__ Wp3,
                                                 unsigned short* __restrict__ Wp4) {
    const int DEGB = (N_EDGES + 255) / 256;  // 2344
    int bid = blockIdx.x;
    if (bid < DEGB) {
        int i = bid * 256 + threadIdx.x;
        if (i < E) atomicAdd(&degi[dst[i]], 1);
    } else {
        int wb = bid - DEGB;
        if (wb < 64) wprep_one(W1, Wp1, 128, wb * 256 + threadIdx.x);
        else if (wb < 128) wprep_one(W2, Wp2, 128, (wb - 64) * 256 + threadIdx.x);
        else if (wb < 192) wprep_one(W3, Wp3, 128, (wb - 128) * 256 + threadIdx.x);
        else wprep_one(W4, Wp4, 64, (wb - 192) * 256 + threadIdx.x);
    }
}

// ---------------- prefix scan (3-kernel hierarchical; proven ~8us) ----------------
__global__ __launch_bounds__(256) void scan_block(const int* __restrict__ in,
                                                  int* __restrict__ excl,
                                                  int* __restrict__ bsum,
                                                  float* __restrict__ dis, int N) {
    __shared__ int s[256];
    int i = blockIdx.x * 256 + threadIdx.x;
    int v = (i < N) ? in[i] : 0;
    s[threadIdx.x] = v;
    __syncthreads();
#pragma unroll
    for (int off = 1; off < 256; off <<= 1) {
        int t = (threadIdx.x >= off) ? s[threadIdx.x - off] : 0;
        __syncthreads();
        s[threadIdx.x] += t;
        __syncthreads();
    }
    if (i < N) {
        excl[i] = s[threadIdx.x] - v;
        dis[i] = rsqrtf((float)v + 1.0f);
    }
    if (threadIdx.x == 255) bsum[blockIdx.x] = s[255];
}

__global__ __launch_bounds__(256) void scan_top(const int* __restrict__ bsum,
                                                int* __restrict__ boff, int NB,
                                                const int* __restrict__ batch,
                                                int* __restrict__ gstart, int N) {
    __shared__ int s[256];
    int v = (threadIdx.x < NB) ? bsum[threadIdx.x] : 0;
    s[threadIdx.x] = v;
    __syncthreads();
#pragma unroll
    for (int off = 1; off < 256; off <<= 1) {
        int t = (threadIdx.x >= off) ? s[threadIdx.x - off] : 0;
        __syncthreads();
        s[threadIdx.x] += t;
        __syncthreads();
    }
    if (threadIdx.x < NB) boff[threadIdx.x] = s[threadIdx.x] - v;

    int g = threadIdx.x;
    if (g <= N_GRAPHS) {
        int lo = 0, hi = N;
        while (lo < hi) {
            int mid = (lo + hi) >> 1;
            if (batch[mid] < g) lo = mid + 1; else hi = mid;
        }
        gstart[g] = lo;
    }
}

__global__ __launch_bounds__(256) void scan_fix(const int* __restrict__ excl,
                                                const int* __restrict__ boff,
                                                int* __restrict__ rowptr,
                                                int* __restrict__ cursor, int N, int E) {
    int i = blockIdx.x * 256 + threadIdx.x;
    if (i < N) {
        int r = excl[i] + boff[blockIdx.x];
        rowptr[i] = r;
        cursor[i] = r;
    }
    if (i == 0) rowptr[N] = E;
}

// ---------------- FUSED: mm1 + XCD-partitioned CSR fill ----------------
// mm1: blocks [0, MM1B). csr: blocks [MM1B, MM1B + 8*CSRB); each edge chunk is
// covered by 8 blocks, block with (bid&7)==p writes only edges whose dst is in
// partition p (contiguous node range). If HW round-robins wg->XCD by bid%8,
// each csr line + its cursor stay in ONE XCD's L2 -> no cross-XCD ping-pong.
#define MM1B ((N_NODES + 63) / 64)        // 782
#define CSRB ((N_EDGES + 255) / 256)      // 2344

__global__ __launch_bounds__(256) void csrfill_mm1(const int* __restrict__ src,
                                                   const int* __restrict__ dst,
                                                   const float* __restrict__ dis,
                                                   int* __restrict__ cursor,
                                                   unsigned int* __restrict__ csr, int E,
                                                   const float* __restrict__ Xf,
                                                   const unsigned short* __restrict__ Wp,
                                                   unsigned short* __restrict__ T, int N) {
    if (blockIdx.x >= MM1B) {
        // ---- CSR fill (partitioned) ----
        const int part = blockIdx.x & 7;
        const int ch = (blockIdx.x - MM1B) >> 3;
        int e = ch * 256 + threadIdx.x;
        if (e >= E) return;
        int d = dst[e];
        if ((d * 8) / N_NODES != part) return;
        int s = src[e];
        float nrm = dis[s] * dis[d];
        unsigned short hb = __half_as_ushort(__float2half(nrm));
        int pos = atomicAdd(&cursor[d], 1);
        csr[pos] = ((unsigned int)s << 16) | (unsigned int)hb;
        return;
    }
    // ---- mm1 ----
    const int lane = threadIdx.x & 63;
    const int wave = threadIdx.x >> 6;
    const int r0 = blockIdx.x * 64 + wave * 16;
    const int kg = lane >> 4;
    const int rdrow = min(r0 + (lane & 15), N - 1);
    const float* xr = Xf + (size_t)rdrow * 128;

    bf16x8 a[4];
#pragma unroll
    for (int ks = 0; ks < 4; ++ks) {
        const int kb = ks * 32 + kg * 8;
        float4 x0 = *reinterpret_cast<const float4*>(xr + kb);
        float4 x1 = *reinterpret_cast<const float4*>(xr + kb + 4);
        float v[8] = {x0.x, x0.y, x0.z, x0.w, x1.x, x1.y, x1.z, x1.w};
#pragma unroll
        for (int i = 0; i < 8; ++i) a[ks][i] = (short)f2bf(v[i]);
    }

#pragma unroll
    for (int ct = 0; ct < 8; ++ct) {
        f32x4 acc = {0.f, 0.f, 0.f, 0.f};
#pragma unroll
        for (int ks = 0; ks < 4; ++ks) {
            bf16x8 b = *reinterpret_cast<const bf16x8*>(Wp + ((size_t)(ct * 4 + ks) * 64 + lane) * 8);
            acc = __builtin_amdgcn_mfma_f32_16x16x32_bf16(a[ks], b, acc, 0, 0, 0);
        }
        const int col = ct * 16 + (lane & 15);
#pragma unroll
        for (int r = 0; r < 4; ++r) {
            const int rowm = r0 + kg * 4 + r;
            if (rowm < N) T[(size_t)rowm * 128 + col] = f2bf(acc[r]);
        }
    }
}

// ---------------- dual-node combined-stream gather (128-feat rows) ----------------
// walks [beg,end) = two adjacent nodes' contiguous csr ranges as ONE 8-deep
// pipelined stream; predicated accumulation into node0 (p<mid) or node1.
__device__ __forceinline__ void gather128x2(int beg, int mid, int end,
                                            const unsigned int* __restrict__ csr,
                                            const unsigned short* __restrict__ T, int lane,
                                            float& ax0, float& ay0, float& ax1, float& ay1) {
    int p = beg;
    for (; p + 8 <= end; p += 8) {
        unsigned int e0 = csr[p], e1 = csr[p + 1], e2 = csr[p + 2], e3 = csr[p + 3];
        unsigned int e4 = csr[p + 4], e5 = csr[p + 5], e6 = csr[p + 6], e7 = csr[p + 7];
        unsigned int r0 = *reinterpret_cast<const unsigned int*>(T + (size_t)(e0 >> 16) * 128 + lane * 2);
        unsigned int r1 = *reinterpret_cast<const unsigned int*>(T + (size_t)(e1 >> 16) * 128 + lane * 2);
        unsigned int r2 = *reinterpret_cast<const unsigned int*>(T + (size_t)(e2 >> 16) * 128 + lane * 2);
        unsigned int r3 = *reinterpret_cast<const unsigned int*>(T + (size_t)(e3 >> 16) * 128 + lane * 2);
        unsigned int r4 = *reinterpret_cast<const unsigned int*>(T + (size_t)(e4 >> 16) * 128 + lane * 2);
        unsigned int r5 = *reinterpret_cast<const unsigned int*>(T + (size_t)(e5 >> 16) * 128 + lane * 2);
        unsigned int r6 = *reinterpret_cast<const unsigned int*>(T + (size_t)(e6 >> 16) * 128 + lane * 2);
        unsigned int r7 = *reinterpret_cast<const unsigned int*>(T + (size_t)(e7 >> 16) * 128 + lane * 2);
#define ACC8(K)                                                                  \
        {                                                                        \
            float n = pnorm(e##K);                                               \
            float na = (p + K < mid) ? n : 0.0f;                                 \
            float nb = (p + K < mid) ? 0.0f : n;                                 \
            ax0 = fmaf(na, bf_lo(r##K), ax0); ay0 = fmaf(na, bf_hi(r##K), ay0);  \
            ax1 = fmaf(nb, bf_lo(r##K), ax1); ay1 = fmaf(nb, bf_hi(r##K), ay1);  \
        }
        ACC8(0) ACC8(1) ACC8(2) ACC8(3) ACC8(4) ACC8(5) ACC8(6) ACC8(7)
#undef ACC8
    }
    for (; p + 4 <= end; p += 4) {
        unsigned int e0 = csr[p], e1 = csr[p + 1], e2 = csr[p + 2], e3 = csr[p + 3];
        unsigned int r0 = *reinterpret_cast<const unsigned int*>(T + (size_t)(e0 >> 16) * 128 + lane * 2);
        unsigned int r1 = *reinterpret_cast<const unsigned int*>(T + (size_t)(e1 >> 16) * 128 + lane * 2);
        unsigned int r2 = *reinterpret_cast<const unsigned int*>(T + (size_t)(e2 >> 16) * 128 + lane * 2);
        unsigned int r3 = *reinterpret_cast<const unsigned int*>(T + (size_t)(e3 >> 16) * 128 + lane * 2);
#define ACC4(K)                                                                  \
        {                                                                        \
            float n = pnorm(e##K);                                               \
            float na = (p + K < mid) ? n : 0.0f;                                 \
            float nb = (p + K < mid) ? 0.0f : n;                                 \
            ax0 = fmaf(na, bf_lo(r##K), ax0); ay0 = fmaf(na, bf_hi(r##K), ay0);  \
            ax1 = fmaf(nb, bf_lo(r##K), ax1); ay1 = fmaf(nb, bf_hi(r##K), ay1);  \
        }
        ACC4(0) ACC4(1) ACC4(2) ACC4(3)
#undef ACC4
    }
    for (; p < end; ++p) {
        unsigned int e = csr[p];
        unsigned int r = *reinterpret_cast<const unsigned int*>(T + (size_t)(e >> 16) * 128 + lane * 2);
        float n = pnorm(e);
        float na = (p < mid) ? n : 0.0f;
        float nb = (p < mid) ? 0.0f : n;
        ax0 = fmaf(na, bf_lo(r), ax0); ay0 = fmaf(na, bf_hi(r), ay0);
        ax1 = fmaf(nb, bf_lo(r), ax1); ay1 = fmaf(nb, bf_hi(r), ay1);
    }
}

// ---------------- FUSED: agg(layer i) + relu + mm(layer i+1) ----------------
// block = 16 nodes, 8 waves (512 thr). wave w gathers its 2 nodes as one
// combined csr stream into LDS; all waves then MFMA, one ct per wave.
// N divisible by 16 -> no bounds checks in gather phase.
template <int FOUT>
__global__ __launch_bounds__(512) void aggmm(const int* __restrict__ rowptr,
                                             const unsigned int* __restrict__ csr,
                                             const float* __restrict__ dis,
                                             const float* __restrict__ b,
                                             const unsigned short* __restrict__ T,
                                             const unsigned short* __restrict__ Wp,
                                             unsigned short* __restrict__ Tout, int N) {
    __shared__ unsigned short hl[16][136];
    const int lane = threadIdx.x & 63;
    const int wave = threadIdx.x >> 6;
    const int r0 = blockIdx.x * 16;
    const float2 bb = *reinterpret_cast<const float2*>(b + lane * 2);

    const int n0 = __builtin_amdgcn_readfirstlane(r0 + wave * 2);
    const int beg = rowptr[n0];
    const int mid = rowptr[n0 + 1];
    const int end = rowptr[n0 + 2];
    const float d0 = dis[n0], d1 = dis[n0 + 1];

    unsigned int s0 = *reinterpret_cast<const unsigned int*>(T + (size_t)n0 * 128 + lane * 2);
    unsigned int s1 = *reinterpret_cast<const unsigned int*>(T + (size_t)(n0 + 1) * 128 + lane * 2);
    float ax0 = fmaf(bf_lo(s0), d0 * d0, bb.x);
    float ay0 = fmaf(bf_hi(s0), d0 * d0, bb.y);
    float ax1 = fmaf(bf_lo(s1), d1 * d1, bb.x);
    float ay1 = fmaf(bf_hi(s1), d1 * d1, bb.y);

    gather128x2(beg, mid, end, csr, T, lane, ax0, ay0, ax1, ay1);

    *reinterpret_cast<unsigned int*>(&hl[wave * 2 + 0][lane * 2]) =
        ((unsigned int)f2bf(ay0) << 16) | (unsigned int)f2bf(ax0);
    *reinterpret_cast<unsigned int*>(&hl[wave * 2 + 1][lane * 2]) =
        ((unsigned int)f2bf(ay1) << 16) | (unsigned int)f2bf(ax1);
    __syncthreads();

    constexpr int NCT = FOUT / 16;  // 8 (F=128) or 4 (F=64)
    if (wave < NCT) {
        const int kg = lane >> 4;
        bf16x8 a[4];
#pragma unroll
        for (int ks = 0; ks < 4; ++ks) {
            bf16x8 av = *reinterpret_cast<const bf16x8*>(&hl[lane & 15][ks * 32 + kg * 8]);
#pragma unroll
            for (int i = 0; i < 8; ++i) av[i] = (av[i] < 0) ? (short)0 : av[i];
            a[ks] = av;
        }

        const int ct = wave;
        f32x4 acc = {0.f, 0.f, 0.f, 0.f};
#pragma unroll
        for (int ks = 0; ks < 4; ++ks) {
            bf16x8 bfr = *reinterpret_cast<const bf16x8*>(Wp + ((size_t)(ct * 4 + ks) * 64 + lane) * 8);
            acc = __builtin_amdgcn_mfma_f32_16x16x32_bf16(a[ks], bfr, acc, 0, 0, 0);
        }
        const int col = ct * 16 + (lane & 15);
#pragma unroll
        for (int r = 0; r < 4; ++r) {
            Tout[(size_t)(r0 + kg * 4 + r) * FOUT + col] = f2bf(acc[r]);
        }
    }
}

// ---------------- final aggregation (layer 4, F=64): dual-node waves ----------------
__global__ __launch_bounds__(256) void agg64(const int* __restrict__ rowptr,
                                             const unsigned int* __restrict__ csr,
                                             const float* __restrict__ dis,
                                             const float* __restrict__ b,
                                             const unsigned short* __restrict__ T,
                                             unsigned short* __restrict__ H, int N) {
    const int lane = threadIdx.x & 63;
    const int n0 = __builtin_amdgcn_readfirstlane(((blockIdx.x * 256 + threadIdx.x) >> 6) * 2);
    if (n0 >= N) return;

    const int beg = rowptr[n0];
    const int mid = rowptr[n0 + 1];
    const int end = rowptr[n0 + 2];
    const float d0 = dis[n0], d1 = dis[n0 + 1];
    const float blane = b[lane];
    float a0 = fmaf(bf1(T[(size_t)n0 * 64 + lane]), d0 * d0, blane);
    float a1 = fmaf(bf1(T[(size_t)(n0 + 1) * 64 + lane]), d1 * d1, blane);

    int p = beg;
    for (; p + 8 <= end; p += 8) {
        unsigned int e0 = csr[p], e1 = csr[p + 1], e2 = csr[p + 2], e3 = csr[p + 3];
        unsigned int e4 = csr[p + 4], e5 = csr[p + 5], e6 = csr[p + 6], e7 = csr[p + 7];
        unsigned short v0 = T[(size_t)(e0 >> 16) * 64 + lane];
        unsigned short v1 = T[(size_t)(e1 >> 16) * 64 + lane];
        unsigned short v2 = T[(size_t)(e2 >> 16) * 64 + lane];
        unsigned short v3 = T[(size_t)(e3 >> 16) * 64 + lane];
        unsigned short v4 = T[(size_t)(e4 >> 16) * 64 + lane];
        unsigned short v5 = T[(size_t)(e5 >> 16) * 64 + lane];
        unsigned short v6 = T[(size_t)(e6 >> 16) * 64 + lane];
        unsigned short v7 = T[(size_t)(e7 >> 16) * 64 + lane];
#define A64(K)                                                       \
        {                                                            \
            float n = pnorm(e##K);                                   \
            float na = (p + K < mid) ? n : 0.0f;                     \
            float nb = (p + K < mid) ? 0.0f : n;                     \
            a0 = fmaf(na, bf1(v##K), a0);                            \
            a1 = fmaf(nb, bf1(v##K), a1);                            \
        }
        A64(0) A64(1) A64(2) A64(3) A64(4) A64(5) A64(6) A64(7)
#undef A64
    }
    for (; p < end; ++p) {
        unsigned int e = csr[p];
        unsigned short v = T[(size_t)(e >> 16) * 64 + lane];
        float n = pnorm(e);
        float na = (p < mid) ? n : 0.0f;
        float nb = (p < mid) ? 0.0f : n;
        a0 = fmaf(na, bf1(v), a0);
        a1 = fmaf(nb, bf1(v), a1);
    }
    H[(size_t)n0 * 64 + lane] = f2bf(a0);
    H[(size_t)(n0 + 1) * 64 + lane] = f2bf(a1);
}

// ---------------- pooling (two-stage deterministic; H is bf16) ----------------
__global__ __launch_bounds__(256) void pool_partial(const unsigned short* __restrict__ H,
                                                    const int* __restrict__ gstart,
                                                    float* __restrict__ partial) {
    const int g = blockIdx.x >> 4;
    const int c = blockIdx.x & (PCHUNK - 1);
    const int beg = gstart[g], end = gstart[g + 1];
    const int len = end - beg;
    const int csz = (len + PCHUNK - 1) / PCHUNK;
    const int cb = beg + c * csz;
    const int ce = min(cb + csz, end);
    const int lane = threadIdx.x & 63;
    const int wave = threadIdx.x >> 6;

    float acc = 0.0f;
    for (int n = cb + wave; n < ce; n += 4)
        acc += bf1(H[(size_t)n * 64 + lane]);

    __shared__ float s[4][64];
    s[wave][lane] = acc;
    __syncthreads();
    if (wave == 0)
        partial[(size_t)(g * PCHUNK + c) * 64 + lane] =
            s[0][lane] + s[1][lane] + s[2][lane] + s[3][lane];
}

__global__ __launch_bounds__(64) void pool_fin(const float* __restrict__ partial,
                                               const int* __restrict__ gstart,
                                               float* __restrict__ out) {
    const int g = blockIdx.x;
    const int lane = threadIdx.x;
    float v = 0.0f;
#pragma unroll
    for (int c = 0; c < PCHUNK; ++c) v += partial[(size_t)(g * PCHUNK + c) * 64 + lane];
    float cnt = (float)(gstart[g + 1] - gstart[g]);
    out[g * 64 + lane] = v / fmaxf(cnt, 1.0f);
}

// ---------------- launch ----------------
extern "C" void kernel_launch(void* const* d_in, const int* in_sizes, int n_in,
                              void* d_out, int out_size, void* d_ws, size_t ws_size,
                              hipStream_t stream) {
    const float* x = (const float*)d_in[0];
    const int* ei = (const int*)d_in[1];
    const int* batch = (const int*)d_in[2];
    const float* W1 = (const float*)d_in[3];
    const float* b1 = (const float*)d_in[4];
    const float* W2 = (const float*)d_in[5];
    const float* b2 = (const float*)d_in[6];
    const float* W3 = (const float*)d_in[7];
    const float* b3 = (const float*)d_in[8];
    const float* W4 = (const float*)d_in[9];
    const float* b4 = (const float*)d_in[10];

    const int N = N_NODES, E = N_EDGES;
    const int* src = ei;
    const int* dst = ei + E;

    // workspace layout (64B-aligned carve-outs)
    char* base = (char*)d_ws;
    size_t off = 0;
    auto carve = [&](size_t bytes) -> void* {
        off = (off + 63) & ~(size_t)63;
        void* p = base + off;
        off += bytes;
        return p;
    };
    unsigned short* Ta = (unsigned short*)carve((size_t)N * 128 * 2);  // bf16 ping
    unsigned short* Tb = (unsigned short*)carve((size_t)N * 128 * 2);  // bf16 pong
    unsigned short* H = (unsigned short*)carve((size_t)N * 64 * 2);   // bf16 (layer-4 out)
    int* degi = (int*)carve((size_t)N * 4);
    float* dis = (float*)carve((size_t)N * 4);
    int* rowptr = (int*)carve((size_t)(N + 1) * 4);
    int* cursor = (int*)carve((size_t)N * 4);
    int* excl = (int*)carve((size_t)N * 4);
    int* bsum = (int*)carve(256 * 4);
    int* boff = (int*)carve(256 * 4);
    unsigned int* csr = (unsigned int*)carve((size_t)E * 4);  // packed {src:16|f16 norm}
    int* gstart = (int*)carve(65 * 4);
    float* partial = (float*)carve((size_t)N_GRAPHS * PCHUNK * 64 * 4);
    unsigned short* Wp1 = (unsigned short*)carve(128 * 128 * 2);
    unsigned short* Wp2 = (unsigned short*)carve(128 * 128 * 2);
    unsigned short* Wp3 = (unsigned short*)carve(128 * 128 * 2);
    unsigned short* Wp4 = (unsigned short*)carve(128 * 64 * 2);

    hipMemsetAsync(degi, 0, N * sizeof(int), stream);

    // ---- prep: degree+wprep -> 3-kernel scan -> fused csr_fill + mm1 ----
    const int NB = (N + 255) / 256;    // 196
    const int DEGB = (E + 255) / 256;  // 2344
    deg_wprep<<<DEGB + 224, 256, 0, stream>>>(dst, degi, E, W1, W2, W3, W4,
                                              Wp1, Wp2, Wp3, Wp4);
    scan_block<<<NB, 256, 0, stream>>>(degi, excl, bsum, dis, N);
    scan_top<<<1, 256, 0, stream>>>(bsum, boff, NB, batch, gstart, N);
    scan_fix<<<NB, 256, 0, stream>>>(excl, boff, rowptr, cursor, N, E);
    csrfill_mm1<<<MM1B + 8 * CSRB, 256, 0, stream>>>(src, dst, dis, cursor, csr, E,
                                                     x, Wp1, Ta, N);

    const int FUS = (N + 15) / 16;  // 3125 (exact)

    // fused agg1 + relu + mm2 -> Tb
    aggmm<128><<<FUS, 512, 0, stream>>>(rowptr, csr, dis, b1, Ta, Wp2, Tb, N);
    // fused agg2 + relu + mm3 -> Ta
    aggmm<128><<<FUS, 512, 0, stream>>>(rowptr, csr, dis, b2, Tb, Wp3, Ta, N);
    // fused agg3 + relu + mm4 -> Tb (F=64)
    aggmm<64><<<FUS, 512, 0, stream>>>(rowptr, csr, dis, b3, Ta, Wp4, Tb, N);
    // final agg (layer 4) -> H
    agg64<<<(N / 2 * 64 + 255) / 256, 256, 0, stream>>>(rowptr, csr, dis, b4, Tb, H, N);

    // global mean pool (two-stage, deterministic)
    pool_partial<<<N_GRAPHS * PCHUNK, 256, 0, stream>>>(H, gstart, partial);
    pool_fin<<<N_GRAPHS, 64, 0, stream>>>(partial, gstart, (float*)d_out);
}